// Round 15
// baseline (102.192 us; speedup 1.0000x reference)
//
#include <hip/hip_runtime.h>
#include <hip/hip_bf16.h>

// TritonDynamicAttention: blocksparse causal attention, B=2,H=16,S=2048,D=64, BLOCK=32.
// R15 = R13 + full K/V double-buffer across the kb loop. Post-R14 model: ~2140cy
// effective per CORE vs ~600cy compute chain -> residual is in-loop load latency
// (8 scattered 16B loads/CORE, V^T lanes stride 4KB = 64 cache lines, only 2
// waves/SIMD of TLP). Prefetching kb+2's K/V tiles while computing kb hides it.
// (128,2) VGPR budget: R13 form ~180 + 48 dbuf = ~205 < 256, no spill.
// Keeps: fp16 carrier, complementary-pair balance, shared K/V loads, kv-parity
// 2-wave split + LDS merge, permlane32_swap, exp2 softmax, defer-max, cvt_pkrtz,
// early-exit block mask, fused prep.

typedef _Float16 f16_t;
typedef f16_t  f16x8  __attribute__((ext_vector_type(8)));
typedef __fp16 fp16x2 __attribute__((ext_vector_type(2)));
typedef float  f32x4  __attribute__((ext_vector_type(4)));
typedef float  f32x16 __attribute__((ext_vector_type(16)));
typedef int    i32x4  __attribute__((ext_vector_type(4)));
typedef int    i32x2  __attribute__((ext_vector_type(2)));
typedef unsigned int u32x4 __attribute__((ext_vector_type(4)));

constexpr int Bc = 2, Hc = 16, Sc = 2048, Dc = 64;
constexpr int NB = Sc / 32;                              // 64 mask blocks per side
constexpr size_t QKV_ELEMS = (size_t)Bc * Hc * Sc * Dc;  // 4194304
constexpr float LOG2E = 1.4426950408889634f;

__device__ inline f32x16 mfma32(f16x8 a, f16x8 b, f32x16 c) {
    return __builtin_amdgcn_mfma_f32_32x32x16_f16(a, b, c, 0, 0, 0);
}
__device__ inline float fexp2(float x) { return __builtin_amdgcn_exp2f(x); }

union UB { u32x4 u; f16x8 v; };
union PK { fp16x2 h; unsigned int u; };

#if __has_builtin(__builtin_amdgcn_permlane32_swap)
#define HAVE_PLSWAP 1
__device__ inline i32x2 plswap(unsigned int a, unsigned int b) {
    return __builtin_amdgcn_permlane32_swap((int)a, (int)b, false, false);
}
__device__ inline float xhalf_max(float x) {
    i32x2 s = plswap((unsigned int)__float_as_int(x), (unsigned int)__float_as_int(x));
    return fmaxf(__int_as_float(s[0]), __int_as_float(s[1]));
}
__device__ inline float xhalf_sum(float x) {
    i32x2 s = plswap((unsigned int)__float_as_int(x), (unsigned int)__float_as_int(x));
    return __int_as_float(s[0]) + __int_as_float(s[1]);
}
#else
#define HAVE_PLSWAP 0
__device__ inline float xhalf_max(float x) { return fmaxf(x, __shfl_xor(x, 32)); }
__device__ inline float xhalf_sum(float x) { return x + __shfl_xor(x, 32); }
#endif

// ---------- fused prep: [0,2048) K->f16 | [2048,3072) V^T f16 | [3072,4096) blockmask --
__global__ __launch_bounds__(256) void k_prep(const float* __restrict__ K,
                                              const float* __restrict__ V,
                                              const int* __restrict__ mask,
                                              const float* __restrict__ bias,
                                              f16_t* __restrict__ kh,
                                              f16_t* __restrict__ vt,
                                              unsigned char* __restrict__ bm) {
    const int bid = blockIdx.x;
    const int t   = threadIdx.x;
    if (bid < 2048) {
        size_t i = ((size_t)bid * 256 + t) * 8;
        f32x4 a = *(const f32x4*)(K + i);
        f32x4 b = *(const f32x4*)(K + i + 4);
        float xs[8] = {a[0], a[1], a[2], a[3], b[0], b[1], b[2], b[3]};
        f16x8 h;
#pragma unroll
        for (int j = 0; j < 8; j++) h[j] = (f16_t)xs[j];
        *(f16x8*)(kh + i) = h;
    } else if (bid < 3072) {
        __shared__ f16_t tile[64 * 66];
        const int b2 = bid - 2048;
        const int bh = b2 >> 5;
        const int st = b2 & 31;
        {
            int sr = t >> 2, dseg = (t & 3) * 16;
            const float* vr = V + ((size_t)bh * Sc + (size_t)st * 64 + sr) * Dc + dseg;
#pragma unroll
            for (int c = 0; c < 4; c++) {
                f32x4 a = *(const f32x4*)(vr + c * 4);
#pragma unroll
                for (int j = 0; j < 4; j++) tile[sr * 66 + dseg + c * 4 + j] = (f16_t)a[j];
            }
        }
        __syncthreads();
        {
            int dr = t >> 2, sseg = (t & 3) * 16;
            f16x8 h0, h1;
#pragma unroll
            for (int j = 0; j < 8; j++) h0[j] = tile[(sseg + j) * 66 + dr];
#pragma unroll
            for (int j = 0; j < 8; j++) h1[j] = tile[(sseg + 8 + j) * 66 + dr];
            f16_t* outp = vt + ((size_t)bh * Dc + dr) * Sc + (size_t)st * 64 + sseg;
            *(f16x8*)outp = h0;
            *(f16x8*)(outp + 8) = h1;
        }
    } else {
        const int b3 = bid - 3072;
        const int h  = b3 >> 6;
        const int br = b3 & 63;
        float bv = bias[h];
        unsigned char* outp = bm + ((size_t)h * NB + br) * NB;
        if (bv > 0.f) {
            if (t < NB) outp[t] = 1;
            return;
        }
        int bc0 = t >> 3;
        int bc1 = 32 + bc0;
        const int* base = mask + ((size_t)h * Sc + (size_t)br * 32) * (size_t)Sc;
        const int* p0 = base + 4 * t;
        const int* p1 = base + 1024 + 4 * t;
        bool d0 = (bc0 <= br), d1 = (bc1 <= br);
        int acc0 = 0, acc1 = 0;
        if (d0) {
#pragma unroll
            for (int r = 0; r < 4; r++) {
                i32x4 vv = *(const i32x4*)(p0 + (size_t)r * Sc);
                acc0 += vv[0] + vv[1] + vv[2] + vv[3];
            }
        }
        if (d1) {
#pragma unroll
            for (int r = 0; r < 4; r++) {
                i32x4 vv = *(const i32x4*)(p1 + (size_t)r * Sc);
                acc1 += vv[0] + vv[1] + vv[2] + vv[3];
            }
        }
        int g0 = acc0, g1 = acc1;
#pragma unroll
        for (int off = 1; off < 8; off <<= 1) {
            g0 += __shfl_xor(g0, off);
            g1 += __shfl_xor(g1, off);
        }
        bool act0 = (float)g0 + bv > 0.f;   // certified active (remaining rows >= 0)
        bool act1 = (float)g1 + bv > 0.f;
        if (d0 && !act0) {
            for (int r = 4; r < 32; r++) {
                i32x4 vv = *(const i32x4*)(p0 + (size_t)r * Sc);
                acc0 += vv[0] + vv[1] + vv[2] + vv[3];
            }
            int s = acc0;
#pragma unroll
            for (int off = 1; off < 8; off <<= 1) s += __shfl_xor(s, off);
            act0 = (float)s + bv > 0.f;
        }
        if (d1 && !act1) {
            for (int r = 4; r < 32; r++) {
                i32x4 vv = *(const i32x4*)(p1 + (size_t)r * Sc);
                acc1 += vv[0] + vv[1] + vv[2] + vv[3];
            }
            int s = acc1;
#pragma unroll
            for (int off = 1; off < 8; off <<= 1) s += __shfl_xor(s, off);
            act1 = (float)s + bv > 0.f;
        }
        if ((t & 7) == 0) {
            if (d0) outp[bc0] = act0 ? 1 : 0;
            if (d1) outp[bc1] = act1 ? 1 : 0;
        }
    }
}

// ---------- flash blocksparse causal attention: pairs + K/V double-buffer ----------
#if HAVE_PLSWAP
#define EXCHANGE_P(PB, B0, B1) do {                                            \
        i32x2 e0_ = plswap(PB[0], PB[2]);                                      \
        i32x2 e1_ = plswap(PB[1], PB[3]);                                      \
        i32x2 e2_ = plswap(PB[4], PB[6]);                                      \
        i32x2 e3_ = plswap(PB[5], PB[7]);                                      \
        B0.u[0] = (unsigned int)e0_[0]; B0.u[1] = (unsigned int)e1_[0];        \
        B0.u[2] = (unsigned int)e0_[1]; B0.u[3] = (unsigned int)e1_[1];        \
        B1.u[0] = (unsigned int)e2_[0]; B1.u[1] = (unsigned int)e3_[0];        \
        B1.u[2] = (unsigned int)e2_[1]; B1.u[3] = (unsigned int)e3_[1];        \
} while (0)
#else
#define EXCHANGE_P(PB, B0, B1) do {                                            \
        unsigned int qb_[8];                                                   \
        _Pragma("unroll")                                                      \
        for (int i_ = 0; i_ < 8; i_++)                                         \
            qb_[i_] = (unsigned int)__shfl_xor((int)PB[i_], 32);               \
        B0.u[0] = hi ? qb_[2] : PB[0]; B0.u[1] = hi ? qb_[3] : PB[1];          \
        B0.u[2] = hi ? PB[2] : qb_[0]; B0.u[3] = hi ? PB[3] : qb_[1];          \
        B1.u[0] = hi ? qb_[6] : PB[4]; B1.u[1] = hi ? qb_[7] : PB[5];          \
        B1.u[2] = hi ? PB[6] : qb_[4]; B1.u[3] = hi ? PB[7] : qb_[5];          \
} while (0)
#endif

#define KVLOAD(KBUF, VBUF, kb_) do {                                           \
        _Pragma("unroll")                                                      \
        for (int kc_ = 0; kc_ < 4; kc_++)                                      \
            KBUF[kc_] = *(const f16x8*)(khp + (size_t)(((kb_) * 32 + l31) * Dc)\
                                        + kc_ * 16 + hi * 8);                  \
        _Pragma("unroll")                                                      \
        for (int t_ = 0; t_ < 2; t_++)                                         \
            _Pragma("unroll")                                                  \
            for (int c_ = 0; c_ < 2; c_++)                                     \
                VBUF[t_][c_] = *(const f16x8*)(vtp + (size_t)(t_ * 32 + l31) * Sc \
                                               + (kb_) * 32 + c_ * 16 + hi * 8);  \
} while (0)

// one tile-chain update from preloaded KBUF/VBUF
#define CORE(OT0, OT1, MR, LR, QH, BROW, kb_, KBUF, VBUF) do {                 \
        f32x16 st;                                                             \
        _Pragma("unroll")                                                      \
        for (int r_ = 0; r_ < 16; r_++) st[r_] = 0.f;                          \
        _Pragma("unroll")                                                      \
        for (int kc_ = 0; kc_ < 4; kc_++)                                      \
            st = mfma32(KBUF[kc_], QH[kc_], st);                               \
        if ((kb_) == (BROW)) {                                                 \
            _Pragma("unroll")                                                  \
            for (int r_ = 0; r_ < 16; r_++) {                                  \
                int kvl_ = (r_ & 3) + 8 * (r_ >> 2) + 4 * hi;                  \
                if (kvl_ > l31) st[r_] = -1e30f;                               \
            }                                                                  \
        }                                                                      \
        float a0_ = fmaxf(fmaxf(st[0], st[1]), st[2]);                         \
        float a1_ = fmaxf(fmaxf(st[3], st[4]), st[5]);                         \
        float a2_ = fmaxf(fmaxf(st[6], st[7]), st[8]);                         \
        float a3_ = fmaxf(fmaxf(st[9], st[10]), st[11]);                       \
        float a4_ = fmaxf(fmaxf(st[12], st[13]), st[14]);                      \
        float b0m_ = fmaxf(fmaxf(a0_, a1_), a2_);                              \
        float b1m_ = fmaxf(fmaxf(a3_, a4_), st[15]);                           \
        float mx_ = xhalf_max(fmaxf(b0m_, b1m_));                              \
        if (__ballot(mx_ > MR + 11.0f)) {                                      \
            float mn_ = fmaxf(MR, mx_);                                        \
            float al_ = fexp2(MR - mn_);                                       \
            MR = mn_;                                                          \
            LR *= al_;                                                         \
            OT0 *= al_; OT1 *= al_;                                            \
        }                                                                      \
        _Pragma("unroll")                                                      \
        for (int r_ = 0; r_ < 16; r_++) st[r_] = fexp2(st[r_] - MR);           \
        {                                                                      \
            float s0 = (st[0] + st[1]) + (st[2] + st[3]);                      \
            float s1 = (st[4] + st[5]) + (st[6] + st[7]);                      \
            float s2 = (st[8] + st[9]) + (st[10] + st[11]);                    \
            float s3 = (st[12] + st[13]) + (st[14] + st[15]);                  \
            LR += ((s0 + s1) + (s2 + s3));                                     \
        }                                                                      \
        unsigned int pb_[8];                                                   \
        _Pragma("unroll")                                                      \
        for (int i_ = 0; i_ < 8; i_++) {                                       \
            PK pk_;                                                            \
            pk_.h = __builtin_amdgcn_cvt_pkrtz(st[2 * i_], st[2 * i_ + 1]);    \
            pb_[i_] = pk_.u;                                                   \
        }                                                                      \
        UB b0_, b1_;                                                           \
        EXCHANGE_P(pb_, b0_, b1_);                                             \
        OT0 = mfma32(VBUF[0][0], b0_.v, OT0);                                  \
        OT0 = mfma32(VBUF[0][1], b1_.v, OT0);                                  \
        OT1 = mfma32(VBUF[1][0], b0_.v, OT1);                                  \
        OT1 = mfma32(VBUF[1][1], b1_.v, OT1);                                  \
} while (0)

// process one kb (both tiles as active) from a named buffer set
#define PROCESS(kb_, KBUF, VBUF) do {                                          \
        const bool aA_ = ((kb_) <= qiA) && ((amA >> (kb_)) & 1ull);            \
        const bool aB_ = ((amB >> (kb_)) & 1ull);                              \
        if (aA_) CORE(oA0, oA1, mA, lA, qhA, qiA, kb_, KBUF, VBUF);            \
        if (aB_) CORE(oB0, oB1, mB, lB, qhB, qiB, kb_, KBUF, VBUF);            \
} while (0)

#define QLOAD(QH, q0_) do {                                                    \
        const float* qr_ = q_ptr + (size_t)((q0_) + l31) * Dc + hi * 8;        \
        _Pragma("unroll")                                                      \
        for (int kc_ = 0; kc_ < 4; kc_++) {                                    \
            f32x4 a_ = *(const f32x4*)(qr_ + kc_ * 16);                        \
            f32x4 b_ = *(const f32x4*)(qr_ + kc_ * 16 + 4);                    \
            float xs_[8] = {a_[0], a_[1], a_[2], a_[3], b_[0], b_[1], b_[2], b_[3]}; \
            _Pragma("unroll")                                                  \
            for (int j_ = 0; j_ < 8; j_++) QH[kc_][j_] = (f16_t)(xs_[j_] * LOG2E); \
        }                                                                      \
} while (0)

#define POST(OT0, OT1, MR, LS) do {                                            \
        _Pragma("unroll")                                                      \
        for (int r_ = 0; r_ < 16; r_++) {                                      \
            int d0_ = (r_ & 3) + 8 * (r_ >> 2) + 4 * hi;                       \
            lds_o[d0_ * 33 + l31]        = OT0[r_];                            \
            lds_o[(d0_ + 32) * 33 + l31] = OT1[r_];                            \
        }                                                                      \
        if (hi == 0) { lds_m[l31] = MR; lds_l[l31] = LS; }                     \
} while (0)

#define MERGE_WRITE(OT0, OT1, MR, LS, q0_) do {                                \
        float m1_ = lds_m[l31], l1_ = lds_l[l31];                              \
        float mm_ = fmaxf(MR, m1_);                                            \
        float c0_ = (MR  > -1e37f) ? fexp2(MR  - mm_) : 0.f;                   \
        float c1_ = (m1_ > -1e37f) ? fexp2(m1_ - mm_) : 0.f;                   \
        float lt_ = LS * c0_ + l1_ * c1_;                                      \
        float inv_ = (lt_ > 0.f) ? (1.f / lt_) : 0.f;                          \
        float* op_ = Out + bh_off + (size_t)((q0_) + l31) * Dc;                \
        _Pragma("unroll")                                                      \
        for (int g_ = 0; g_ < 4; g_++) {                                       \
            f32x4 w0_, w1_;                                                    \
            _Pragma("unroll")                                                  \
            for (int jj_ = 0; jj_ < 4; jj_++) {                                \
                int r_ = g_ * 4 + jj_;                                         \
                int d0_ = jj_ + 8 * g_ + 4 * hi;                               \
                w0_[jj_] = (OT0[r_] * c0_ + lds_o[d0_ * 33 + l31] * c1_) * inv_;        \
                w1_[jj_] = (OT1[r_] * c0_ + lds_o[(d0_ + 32) * 33 + l31] * c1_) * inv_; \
            }                                                                  \
            *(f32x4*)(op_ + g_ * 8 + hi * 4)      = w0_;                       \
            *(f32x4*)(op_ + 32 + g_ * 8 + hi * 4) = w1_;                       \
        }                                                                      \
} while (0)

__global__ __launch_bounds__(128, 2) void k_attn(const float* __restrict__ Q,
                                                 const f16_t* __restrict__ KH,
                                                 const f16_t* __restrict__ VT,
                                                 const unsigned char* __restrict__ BM,
                                                 float* __restrict__ Out) {
    __shared__ float lds_o[64 * 33];
    __shared__ float lds_m[32];
    __shared__ float lds_l[32];

    const int pair = blockIdx.x >> 5;              // 0..31
    const int bh   = blockIdx.x & 31;
    const int h    = bh & (Hc - 1);
    const int w    = threadIdx.x >> 6;
    const int lane = threadIdx.x & 63;
    const int l31  = lane & 31, hi = lane >> 5;

    const size_t bh_off = (size_t)bh * Sc * Dc;
    const float* q_ptr  = Q  + bh_off;
    const f16_t* khp    = KH + bh_off;
    const f16_t* vtp    = VT + bh_off;

    const int qiA = pair, qiB = 63 - pair;         // qiA <= 31 < qiB
    const unsigned char* bmA = BM + ((size_t)h * NB + qiA) * NB;
    const unsigned char* bmB = BM + ((size_t)h * NB + qiB) * NB;
    const unsigned long long amA = __ballot(bmA[lane] != 0);
    const unsigned long long amB = __ballot(bmB[lane] != 0);

    f16x8 qhA[4], qhB[4];
    QLOAD(qhA, qiA * 32);
    QLOAD(qhB, qiB * 32);

    f32x16 oA0, oA1, oB0, oB1;
#pragma unroll
    for (int r = 0; r < 16; r++) { oA0[r] = 0.f; oA1[r] = 0.f; oB0[r] = 0.f; oB1[r] = 0.f; }
    float mA = -INFINITY, lA = 0.f, mB = -INFINITY, lB = 0.f;

    // this wave handles kb == w (mod 2); K/V double-buffered (prefetch distance 2)
    f16x8 kX[4], vX[2][2], kY[4], vY[2][2];
    int kb = w;
    if (kb <= qiB) KVLOAD(kX, vX, kb);
    while (kb <= qiB) {
        if (kb + 2 <= qiB) KVLOAD(kY, vY, kb + 2);
        PROCESS(kb, kX, vX);
        kb += 2;
        if (kb > qiB) break;
        if (kb + 2 <= qiB) KVLOAD(kX, vX, kb + 2);
        PROCESS(kb, kY, vY);
        kb += 2;
    }

    const float lsA = xhalf_sum(lA);
    const float lsB = xhalf_sum(lB);

    // two-phase merge through one LDS buffer (epilogue only)
    if (w == 1) POST(oA0, oA1, mA, lsA);
    __syncthreads();
    if (w == 0) MERGE_WRITE(oA0, oA1, mA, lsA, qiA * 32);
    __syncthreads();
    if (w == 0) POST(oB0, oB1, mB, lsB);
    __syncthreads();
    if (w == 1) MERGE_WRITE(oB0, oB1, mB, lsB, qiB * 32);
}

extern "C" void kernel_launch(void* const* d_in, const int* in_sizes, int n_in,
                              void* d_out, int out_size, void* d_ws, size_t ws_size,
                              hipStream_t stream) {
    const float* Q    = (const float*)d_in[0];
    const float* K    = (const float*)d_in[1];
    const float* V    = (const float*)d_in[2];
    const float* bias = (const float*)d_in[3];
    const int*   mask = (const int*)d_in[4];
    float* out = (float*)d_out;

    char* ws = (char*)d_ws;
    f16_t* kh = (f16_t*)ws;                                    // 8 MiB
    f16_t* vt = (f16_t*)(ws + QKV_ELEMS * 2);                  // 8 MiB
    unsigned char* bm = (unsigned char*)(ws + QKV_ELEMS * 4);  // 64 KiB

    k_prep <<<4096, 256, 0, stream>>>(K, V, mask, bias, kh, vt, bm);
    k_attn <<<Hc * Bc * (NB / 2), 128, 0, stream>>>(Q, kh, vt, bm, out);
}

// Round 16
// 69.774 us; speedup vs baseline: 1.4646x; 1.4646x over previous
//
#include <hip/hip_runtime.h>
#include <hip/hip_bf16.h>

// TritonDynamicAttention: blocksparse causal attention, B=2,H=16,S=2048,D=64, BLOCK=32.
// R16 = R13 + K-ONLY prefetch (distance 2). R15's K+V dbuf (+48 VGPR) spilled past the
// 256 cap (R13 is ~220 live, not ~180) -> 102us. V's latency is already hidden (loaded
// at loop top, consumed at PV ~400cy later); only K is consumed immediately -> prefetch
// K alone (+16 VGPR, inside headroom). R14's merged dual-CORE dropped (neutral).
// Keeps: fp16 carrier, complementary-pair balance (65 steps/WG), shared K/V loads,
// kv-parity 2-wave split + LDS merge, permlane32_swap, exp2 softmax w/ log2e-folded Q,
// defer-max, cvt_pkrtz, early-exit block mask, fused prep.

typedef _Float16 f16_t;
typedef f16_t  f16x8  __attribute__((ext_vector_type(8)));
typedef __fp16 fp16x2 __attribute__((ext_vector_type(2)));
typedef float  f32x4  __attribute__((ext_vector_type(4)));
typedef float  f32x16 __attribute__((ext_vector_type(16)));
typedef int    i32x4  __attribute__((ext_vector_type(4)));
typedef int    i32x2  __attribute__((ext_vector_type(2)));
typedef unsigned int u32x4 __attribute__((ext_vector_type(4)));

constexpr int Bc = 2, Hc = 16, Sc = 2048, Dc = 64;
constexpr int NB = Sc / 32;                              // 64 mask blocks per side
constexpr size_t QKV_ELEMS = (size_t)Bc * Hc * Sc * Dc;  // 4194304
constexpr float LOG2E = 1.4426950408889634f;

__device__ inline f32x16 mfma32(f16x8 a, f16x8 b, f32x16 c) {
    return __builtin_amdgcn_mfma_f32_32x32x16_f16(a, b, c, 0, 0, 0);
}
__device__ inline float fexp2(float x) { return __builtin_amdgcn_exp2f(x); }

union UB { u32x4 u; f16x8 v; };
union PK { fp16x2 h; unsigned int u; };

#if __has_builtin(__builtin_amdgcn_permlane32_swap)
#define HAVE_PLSWAP 1
__device__ inline i32x2 plswap(unsigned int a, unsigned int b) {
    return __builtin_amdgcn_permlane32_swap((int)a, (int)b, false, false);
}
__device__ inline float xhalf_max(float x) {
    i32x2 s = plswap((unsigned int)__float_as_int(x), (unsigned int)__float_as_int(x));
    return fmaxf(__int_as_float(s[0]), __int_as_float(s[1]));
}
__device__ inline float xhalf_sum(float x) {
    i32x2 s = plswap((unsigned int)__float_as_int(x), (unsigned int)__float_as_int(x));
    return __int_as_float(s[0]) + __int_as_float(s[1]);
}
#else
#define HAVE_PLSWAP 0
__device__ inline float xhalf_max(float x) { return fmaxf(x, __shfl_xor(x, 32)); }
__device__ inline float xhalf_sum(float x) { return x + __shfl_xor(x, 32); }
#endif

// ---------- fused prep: [0,2048) K->f16 | [2048,3072) V^T f16 | [3072,4096) blockmask --
__global__ __launch_bounds__(256) void k_prep(const float* __restrict__ K,
                                              const float* __restrict__ V,
                                              const int* __restrict__ mask,
                                              const float* __restrict__ bias,
                                              f16_t* __restrict__ kh,
                                              f16_t* __restrict__ vt,
                                              unsigned char* __restrict__ bm) {
    const int bid = blockIdx.x;
    const int t   = threadIdx.x;
    if (bid < 2048) {
        size_t i = ((size_t)bid * 256 + t) * 8;
        f32x4 a = *(const f32x4*)(K + i);
        f32x4 b = *(const f32x4*)(K + i + 4);
        float xs[8] = {a[0], a[1], a[2], a[3], b[0], b[1], b[2], b[3]};
        f16x8 h;
#pragma unroll
        for (int j = 0; j < 8; j++) h[j] = (f16_t)xs[j];
        *(f16x8*)(kh + i) = h;
    } else if (bid < 3072) {
        __shared__ f16_t tile[64 * 66];
        const int b2 = bid - 2048;
        const int bh = b2 >> 5;
        const int st = b2 & 31;
        {
            int sr = t >> 2, dseg = (t & 3) * 16;
            const float* vr = V + ((size_t)bh * Sc + (size_t)st * 64 + sr) * Dc + dseg;
#pragma unroll
            for (int c = 0; c < 4; c++) {
                f32x4 a = *(const f32x4*)(vr + c * 4);
#pragma unroll
                for (int j = 0; j < 4; j++) tile[sr * 66 + dseg + c * 4 + j] = (f16_t)a[j];
            }
        }
        __syncthreads();
        {
            int dr = t >> 2, sseg = (t & 3) * 16;
            f16x8 h0, h1;
#pragma unroll
            for (int j = 0; j < 8; j++) h0[j] = tile[(sseg + j) * 66 + dr];
#pragma unroll
            for (int j = 0; j < 8; j++) h1[j] = tile[(sseg + 8 + j) * 66 + dr];
            f16_t* outp = vt + ((size_t)bh * Dc + dr) * Sc + (size_t)st * 64 + sseg;
            *(f16x8*)outp = h0;
            *(f16x8*)(outp + 8) = h1;
        }
    } else {
        const int b3 = bid - 3072;
        const int h  = b3 >> 6;
        const int br = b3 & 63;
        float bv = bias[h];
        unsigned char* outp = bm + ((size_t)h * NB + br) * NB;
        if (bv > 0.f) {
            if (t < NB) outp[t] = 1;
            return;
        }
        int bc0 = t >> 3;
        int bc1 = 32 + bc0;
        const int* base = mask + ((size_t)h * Sc + (size_t)br * 32) * (size_t)Sc;
        const int* p0 = base + 4 * t;
        const int* p1 = base + 1024 + 4 * t;
        bool d0 = (bc0 <= br), d1 = (bc1 <= br);
        int acc0 = 0, acc1 = 0;
        if (d0) {
#pragma unroll
            for (int r = 0; r < 4; r++) {
                i32x4 vv = *(const i32x4*)(p0 + (size_t)r * Sc);
                acc0 += vv[0] + vv[1] + vv[2] + vv[3];
            }
        }
        if (d1) {
#pragma unroll
            for (int r = 0; r < 4; r++) {
                i32x4 vv = *(const i32x4*)(p1 + (size_t)r * Sc);
                acc1 += vv[0] + vv[1] + vv[2] + vv[3];
            }
        }
        int g0 = acc0, g1 = acc1;
#pragma unroll
        for (int off = 1; off < 8; off <<= 1) {
            g0 += __shfl_xor(g0, off);
            g1 += __shfl_xor(g1, off);
        }
        bool act0 = (float)g0 + bv > 0.f;   // certified active (remaining rows >= 0)
        bool act1 = (float)g1 + bv > 0.f;
        if (d0 && !act0) {
            for (int r = 4; r < 32; r++) {
                i32x4 vv = *(const i32x4*)(p0 + (size_t)r * Sc);
                acc0 += vv[0] + vv[1] + vv[2] + vv[3];
            }
            int s = acc0;
#pragma unroll
            for (int off = 1; off < 8; off <<= 1) s += __shfl_xor(s, off);
            act0 = (float)s + bv > 0.f;
        }
        if (d1 && !act1) {
            for (int r = 4; r < 32; r++) {
                i32x4 vv = *(const i32x4*)(p1 + (size_t)r * Sc);
                acc1 += vv[0] + vv[1] + vv[2] + vv[3];
            }
            int s = acc1;
#pragma unroll
            for (int off = 1; off < 8; off <<= 1) s += __shfl_xor(s, off);
            act1 = (float)s + bv > 0.f;
        }
        if ((t & 7) == 0) {
            if (d0) outp[bc0] = act0 ? 1 : 0;
            if (d1) outp[bc1] = act1 ? 1 : 0;
        }
    }
}

// ---------- flash blocksparse causal attention: pairs + K-only prefetch ----------
#if HAVE_PLSWAP
#define EXCHANGE_P(PB, B0, B1) do {                                            \
        i32x2 e0_ = plswap(PB[0], PB[2]);                                      \
        i32x2 e1_ = plswap(PB[1], PB[3]);                                      \
        i32x2 e2_ = plswap(PB[4], PB[6]);                                      \
        i32x2 e3_ = plswap(PB[5], PB[7]);                                      \
        B0.u[0] = (unsigned int)e0_[0]; B0.u[1] = (unsigned int)e1_[0];        \
        B0.u[2] = (unsigned int)e0_[1]; B0.u[3] = (unsigned int)e1_[1];        \
        B1.u[0] = (unsigned int)e2_[0]; B1.u[1] = (unsigned int)e3_[0];        \
        B1.u[2] = (unsigned int)e2_[1]; B1.u[3] = (unsigned int)e3_[1];        \
} while (0)
#else
#define EXCHANGE_P(PB, B0, B1) do {                                            \
        unsigned int qb_[8];                                                   \
        _Pragma("unroll")                                                      \
        for (int i_ = 0; i_ < 8; i_++)                                         \
            qb_[i_] = (unsigned int)__shfl_xor((int)PB[i_], 32);               \
        B0.u[0] = hi ? qb_[2] : PB[0]; B0.u[1] = hi ? qb_[3] : PB[1];          \
        B0.u[2] = hi ? PB[2] : qb_[0]; B0.u[3] = hi ? PB[3] : qb_[1];          \
        B1.u[0] = hi ? qb_[6] : PB[4]; B1.u[1] = hi ? qb_[7] : PB[5];          \
        B1.u[2] = hi ? PB[6] : qb_[4]; B1.u[3] = hi ? PB[7] : qb_[5];          \
} while (0)
#endif

#define KLOADK(KBUF, kb_) do {                                                 \
        _Pragma("unroll")                                                      \
        for (int kc_ = 0; kc_ < 4; kc_++)                                      \
            KBUF[kc_] = *(const f16x8*)(khp + (size_t)(((kb_) * 32 + l31) * Dc)\
                                        + kc_ * 16 + hi * 8);                  \
} while (0)

// one tile-chain update; K from prefetched KBUF, V from va_ (loaded in PROCESS)
#define CORE(OT0, OT1, MR, LR, QH, BROW, kb_, KBUF) do {                       \
        f32x16 st;                                                             \
        _Pragma("unroll")                                                      \
        for (int r_ = 0; r_ < 16; r_++) st[r_] = 0.f;                          \
        _Pragma("unroll")                                                      \
        for (int kc_ = 0; kc_ < 4; kc_++)                                      \
            st = mfma32(KBUF[kc_], QH[kc_], st);                               \
        if ((kb_) == (BROW)) {                                                 \
            _Pragma("unroll")                                                  \
            for (int r_ = 0; r_ < 16; r_++) {                                  \
                int kvl_ = (r_ & 3) + 8 * (r_ >> 2) + 4 * hi;                  \
                if (kvl_ > l31) st[r_] = -1e30f;                               \
            }                                                                  \
        }                                                                      \
        float a0_ = fmaxf(fmaxf(st[0], st[1]), st[2]);                         \
        float a1_ = fmaxf(fmaxf(st[3], st[4]), st[5]);                         \
        float a2_ = fmaxf(fmaxf(st[6], st[7]), st[8]);                         \
        float a3_ = fmaxf(fmaxf(st[9], st[10]), st[11]);                       \
        float a4_ = fmaxf(fmaxf(st[12], st[13]), st[14]);                      \
        float b0m_ = fmaxf(fmaxf(a0_, a1_), a2_);                              \
        float b1m_ = fmaxf(fmaxf(a3_, a4_), st[15]);                           \
        float mx_ = xhalf_max(fmaxf(b0m_, b1m_));                              \
        if (__ballot(mx_ > MR + 11.0f)) {                                      \
            float mn_ = fmaxf(MR, mx_);                                        \
            float al_ = fexp2(MR - mn_);                                       \
            MR = mn_;                                                          \
            LR *= al_;                                                         \
            OT0 *= al_; OT1 *= al_;                                            \
        }                                                                      \
        _Pragma("unroll")                                                      \
        for (int r_ = 0; r_ < 16; r_++) st[r_] = fexp2(st[r_] - MR);           \
        {                                                                      \
            float s0 = (st[0] + st[1]) + (st[2] + st[3]);                      \
            float s1 = (st[4] + st[5]) + (st[6] + st[7]);                      \
            float s2 = (st[8] + st[9]) + (st[10] + st[11]);                    \
            float s3 = (st[12] + st[13]) + (st[14] + st[15]);                  \
            LR += ((s0 + s1) + (s2 + s3));                                     \
        }                                                                      \
        unsigned int pb_[8];                                                   \
        _Pragma("unroll")                                                      \
        for (int i_ = 0; i_ < 8; i_++) {                                       \
            PK pk_;                                                            \
            pk_.h = __builtin_amdgcn_cvt_pkrtz(st[2 * i_], st[2 * i_ + 1]);    \
            pb_[i_] = pk_.u;                                                   \
        }                                                                      \
        UB b0_, b1_;                                                           \
        EXCHANGE_P(pb_, b0_, b1_);                                             \
        OT0 = mfma32(va_[0][0], b0_.v, OT0);                                   \
        OT0 = mfma32(va_[0][1], b1_.v, OT0);                                   \
        OT1 = mfma32(va_[1][0], b0_.v, OT1);                                   \
        OT1 = mfma32(va_[1][1], b1_.v, OT1);                                   \
} while (0)

// process one kb using prefetched K buffer; V loaded here (hidden under QK+softmax)
#define PROCESS(kb_, KBUF) do {                                                \
        const bool aA_ = ((kb_) <= qiA) && ((amA >> (kb_)) & 1ull);            \
        const bool aB_ = ((amB >> (kb_)) & 1ull);                              \
        if (aA_ || aB_) {                                                      \
            f16x8 va_[2][2];                                                   \
            _Pragma("unroll")                                                  \
            for (int t_ = 0; t_ < 2; t_++)                                     \
                _Pragma("unroll")                                              \
                for (int c_ = 0; c_ < 2; c_++)                                 \
                    va_[t_][c_] = *(const f16x8*)(vtp + (size_t)(t_ * 32 + l31) * Sc \
                                                  + (kb_) * 32 + c_ * 16 + hi * 8);  \
            if (aA_) CORE(oA0, oA1, mA, lA, qhA, qiA, kb_, KBUF);              \
            if (aB_) CORE(oB0, oB1, mB, lB, qhB, qiB, kb_, KBUF);              \
        }                                                                      \
} while (0)

#define QLOAD(QH, q0_) do {                                                    \
        const float* qr_ = q_ptr + (size_t)((q0_) + l31) * Dc + hi * 8;        \
        _Pragma("unroll")                                                      \
        for (int kc_ = 0; kc_ < 4; kc_++) {                                    \
            f32x4 a_ = *(const f32x4*)(qr_ + kc_ * 16);                        \
            f32x4 b_ = *(const f32x4*)(qr_ + kc_ * 16 + 4);                    \
            float xs_[8] = {a_[0], a_[1], a_[2], a_[3], b_[0], b_[1], b_[2], b_[3]}; \
            _Pragma("unroll")                                                  \
            for (int j_ = 0; j_ < 8; j_++) QH[kc_][j_] = (f16_t)(xs_[j_] * LOG2E); \
        }                                                                      \
} while (0)

#define POST(OT0, OT1, MR, LS) do {                                            \
        _Pragma("unroll")                                                      \
        for (int r_ = 0; r_ < 16; r_++) {                                      \
            int d0_ = (r_ & 3) + 8 * (r_ >> 2) + 4 * hi;                       \
            lds_o[d0_ * 33 + l31]        = OT0[r_];                            \
            lds_o[(d0_ + 32) * 33 + l31] = OT1[r_];                            \
        }                                                                      \
        if (hi == 0) { lds_m[l31] = MR; lds_l[l31] = LS; }                     \
} while (0)

#define MERGE_WRITE(OT0, OT1, MR, LS, q0_) do {                                \
        float m1_ = lds_m[l31], l1_ = lds_l[l31];                              \
        float mm_ = fmaxf(MR, m1_);                                            \
        float c0_ = (MR  > -1e37f) ? fexp2(MR  - mm_) : 0.f;                   \
        float c1_ = (m1_ > -1e37f) ? fexp2(m1_ - mm_) : 0.f;                   \
        float lt_ = LS * c0_ + l1_ * c1_;                                      \
        float inv_ = (lt_ > 0.f) ? (1.f / lt_) : 0.f;                          \
        float* op_ = Out + bh_off + (size_t)((q0_) + l31) * Dc;                \
        _Pragma("unroll")                                                      \
        for (int g_ = 0; g_ < 4; g_++) {                                       \
            f32x4 w0_, w1_;                                                    \
            _Pragma("unroll")                                                  \
            for (int jj_ = 0; jj_ < 4; jj_++) {                                \
                int r_ = g_ * 4 + jj_;                                         \
                int d0_ = jj_ + 8 * g_ + 4 * hi;                               \
                w0_[jj_] = (OT0[r_] * c0_ + lds_o[d0_ * 33 + l31] * c1_) * inv_;        \
                w1_[jj_] = (OT1[r_] * c0_ + lds_o[(d0_ + 32) * 33 + l31] * c1_) * inv_; \
            }                                                                  \
            *(f32x4*)(op_ + g_ * 8 + hi * 4)      = w0_;                       \
            *(f32x4*)(op_ + 32 + g_ * 8 + hi * 4) = w1_;                       \
        }                                                                      \
} while (0)

__global__ __launch_bounds__(128, 2) void k_attn(const float* __restrict__ Q,
                                                 const f16_t* __restrict__ KH,
                                                 const f16_t* __restrict__ VT,
                                                 const unsigned char* __restrict__ BM,
                                                 float* __restrict__ Out) {
    __shared__ float lds_o[64 * 33];
    __shared__ float lds_m[32];
    __shared__ float lds_l[32];

    const int pair = blockIdx.x >> 5;              // 0..31
    const int bh   = blockIdx.x & 31;
    const int h    = bh & (Hc - 1);
    const int w    = threadIdx.x >> 6;
    const int lane = threadIdx.x & 63;
    const int l31  = lane & 31, hi = lane >> 5;

    const size_t bh_off = (size_t)bh * Sc * Dc;
    const float* q_ptr  = Q  + bh_off;
    const f16_t* khp    = KH + bh_off;
    const f16_t* vtp    = VT + bh_off;

    const int qiA = pair, qiB = 63 - pair;         // qiA <= 31 < qiB
    const unsigned char* bmA = BM + ((size_t)h * NB + qiA) * NB;
    const unsigned char* bmB = BM + ((size_t)h * NB + qiB) * NB;
    const unsigned long long amA = __ballot(bmA[lane] != 0);
    const unsigned long long amB = __ballot(bmB[lane] != 0);

    f16x8 qhA[4], qhB[4];
    QLOAD(qhA, qiA * 32);
    QLOAD(qhB, qiB * 32);

    f32x16 oA0, oA1, oB0, oB1;
#pragma unroll
    for (int r = 0; r < 16; r++) { oA0[r] = 0.f; oA1[r] = 0.f; oB0[r] = 0.f; oB1[r] = 0.f; }
    float mA = -INFINITY, lA = 0.f, mB = -INFINITY, lB = 0.f;

    // this wave handles kb == w (mod 2); K prefetched (distance 2), V loaded in-step
    f16x8 kX[4], kY[4];
    int kb = w;
    if (kb <= qiB) KLOADK(kX, kb);
    while (kb <= qiB) {
        if (kb + 2 <= qiB) KLOADK(kY, kb + 2);
        PROCESS(kb, kX);
        kb += 2;
        if (kb > qiB) break;
        if (kb + 2 <= qiB) KLOADK(kX, kb + 2);
        PROCESS(kb, kY);
        kb += 2;
    }

    const float lsA = xhalf_sum(lA);
    const float lsB = xhalf_sum(lB);

    // two-phase merge through one LDS buffer (epilogue only)
    if (w == 1) POST(oA0, oA1, mA, lsA);
    __syncthreads();
    if (w == 0) MERGE_WRITE(oA0, oA1, mA, lsA, qiA * 32);
    __syncthreads();
    if (w == 0) POST(oB0, oB1, mB, lsB);
    __syncthreads();
    if (w == 1) MERGE_WRITE(oB0, oB1, mB, lsB, qiB * 32);
}

extern "C" void kernel_launch(void* const* d_in, const int* in_sizes, int n_in,
                              void* d_out, int out_size, void* d_ws, size_t ws_size,
                              hipStream_t stream) {
    const float* Q    = (const float*)d_in[0];
    const float* K    = (const float*)d_in[1];
    const float* V    = (const float*)d_in[2];
    const float* bias = (const float*)d_in[3];
    const int*   mask = (const int*)d_in[4];
    float* out = (float*)d_out;

    char* ws = (char*)d_ws;
    f16_t* kh = (f16_t*)ws;                                    // 8 MiB
    f16_t* vt = (f16_t*)(ws + QKV_ELEMS * 2);                  // 8 MiB
    unsigned char* bm = (unsigned char*)(ws + QKV_ELEMS * 4);  // 64 KiB

    k_prep <<<4096, 256, 0, stream>>>(K, V, mask, bias, kh, vt, bm);
    k_attn <<<Hc * Bc * (NB / 2), 128, 0, stream>>>(Q, kh, vt, bm, out);
}

// Round 17
// 46.717 us; speedup vs baseline: 2.1875x; 1.4935x over previous
//
#include <hip/hip_runtime.h>
#include <hip/hip_bf16.h>

// TritonDynamicAttention: blocksparse causal attention, B=2,H=16,S=2048,D=64, BLOCK=32.
// R17: FRAGMENT-PACKED operand layouts. Diagnosis: k_attn's 8 loads/CORE are
// lane-divergent (K lanes stride 128B, V^T lanes stride 4KB) -> 64 cache lines per
// wave64 load -> per-CU L1 processes ~512cy/CORE; x65 COREs x4 SIMDs = ~55us — the
// measured wall. Fix: k_prep writes K/V in the EXACT lane order the wave reads:
// khf[bh][kb][kc][lane][8f16], vaf[bh][kb][t][c][lane][8f16]; k_attn loads become
// base + lane*16B (coalesced 1KB). Attention core = R13 (complementary pairs,
// kv-parity 2-wave split + LDS merge, permlane32_swap, exp2 softmax, defer-max,
// cvt_pkrtz, early-exit block mask).

typedef _Float16 f16_t;
typedef f16_t  f16x8  __attribute__((ext_vector_type(8)));
typedef __fp16 fp16x2 __attribute__((ext_vector_type(2)));
typedef float  f32x4  __attribute__((ext_vector_type(4)));
typedef float  f32x16 __attribute__((ext_vector_type(16)));
typedef int    i32x4  __attribute__((ext_vector_type(4)));
typedef int    i32x2  __attribute__((ext_vector_type(2)));
typedef unsigned int u32x4 __attribute__((ext_vector_type(4)));

constexpr int Bc = 2, Hc = 16, Sc = 2048, Dc = 64;
constexpr int NB = Sc / 32;                              // 64 mask blocks per side
constexpr float LOG2E = 1.4426950408889634f;
// per-bh fragment array: 64 kb * 4 frags * 64 lanes * 8 f16 = 131072 f16 (256 KiB)
constexpr size_t FRAG_BH = (size_t)NB * 4 * 64 * 8;

__device__ inline f32x16 mfma32(f16x8 a, f16x8 b, f32x16 c) {
    return __builtin_amdgcn_mfma_f32_32x32x16_f16(a, b, c, 0, 0, 0);
}
__device__ inline float fexp2(float x) { return __builtin_amdgcn_exp2f(x); }

union UB { u32x4 u; f16x8 v; };
union PK { fp16x2 h; unsigned int u; };

#if __has_builtin(__builtin_amdgcn_permlane32_swap)
#define HAVE_PLSWAP 1
__device__ inline i32x2 plswap(unsigned int a, unsigned int b) {
    return __builtin_amdgcn_permlane32_swap((int)a, (int)b, false, false);
}
__device__ inline float xhalf_max(float x) {
    i32x2 s = plswap((unsigned int)__float_as_int(x), (unsigned int)__float_as_int(x));
    return fmaxf(__int_as_float(s[0]), __int_as_float(s[1]));
}
__device__ inline float xhalf_sum(float x) {
    i32x2 s = plswap((unsigned int)__float_as_int(x), (unsigned int)__float_as_int(x));
    return __int_as_float(s[0]) + __int_as_float(s[1]);
}
#else
#define HAVE_PLSWAP 0
__device__ inline float xhalf_max(float x) { return fmaxf(x, __shfl_xor(x, 32)); }
__device__ inline float xhalf_sum(float x) { return x + __shfl_xor(x, 32); }
#endif

// ---------- fused prep ----------
// [0,2048): K fragment-pack | [2048,4096): V fragment-pack | [4096,5120): blockmask
__global__ __launch_bounds__(256) void k_prep(const float* __restrict__ K,
                                              const float* __restrict__ V,
                                              const int* __restrict__ mask,
                                              const float* __restrict__ bias,
                                              f16_t* __restrict__ khf,
                                              f16_t* __restrict__ vaf,
                                              unsigned char* __restrict__ bm) {
    __shared__ f16_t tile[32 * 66];
    const int bid = blockIdx.x;
    const int t   = threadIdx.x;
    if (bid < 2048) {
        // ---- K pack: block (bh, kb) = K[bh][kb*32 .. +32][0..64] ----
        const int bh = bid >> 6, kb = bid & 63;
        const float* src = K + ((size_t)bh * Sc + (size_t)kb * 32) * Dc;
        {
            int r = t >> 3, c8 = (t & 7) * 8;      // coalesced read: 8 f32/thread
            f32x4 a = *(const f32x4*)(src + r * Dc + c8);
            f32x4 b = *(const f32x4*)(src + r * Dc + c8 + 4);
            float xs[8] = {a[0], a[1], a[2], a[3], b[0], b[1], b[2], b[3]};
#pragma unroll
            for (int j = 0; j < 8; j++) tile[r * 66 + c8 + j] = (f16_t)xs[j];
        }
        __syncthreads();
        {
            int kc = t >> 6, lane = t & 63, l31 = lane & 31, hi2 = (lane >> 5) & 1;
            f16x8 frag;
#pragma unroll
            for (int j = 0; j < 8; j++)
                frag[j] = tile[l31 * 66 + kc * 16 + hi2 * 8 + j];
            *(f16x8*)(khf + (((size_t)(bh * NB + kb) * 4 + kc) * 64 + lane) * 8) = frag;
        }
    } else if (bid < 4096) {
        // ---- V pack: block (bh, kb) = V[bh][kb*32 .. +32][0..64], frag = V^T ----
        const int b2 = bid - 2048;
        const int bh = b2 >> 6, kb = b2 & 63;
        const float* src = V + ((size_t)bh * Sc + (size_t)kb * 32) * Dc;
        {
            int r = t >> 3, c8 = (t & 7) * 8;      // tile[s][d]
            f32x4 a = *(const f32x4*)(src + r * Dc + c8);
            f32x4 b = *(const f32x4*)(src + r * Dc + c8 + 4);
            float xs[8] = {a[0], a[1], a[2], a[3], b[0], b[1], b[2], b[3]};
#pragma unroll
            for (int j = 0; j < 8; j++) tile[r * 66 + c8 + j] = (f16_t)xs[j];
        }
        __syncthreads();
        {
            int f = t >> 6, lane = t & 63, l31 = lane & 31, hi2 = (lane >> 5) & 1;
            int tt = f >> 1, c = f & 1;
            f16x8 frag;                            // frag[j] = V[kb*32+c*16+hi*8+j][tt*32+l31]
#pragma unroll
            for (int j = 0; j < 8; j++)
                frag[j] = tile[(c * 16 + hi2 * 8 + j) * 66 + tt * 32 + l31];
            *(f16x8*)(vaf + (((size_t)(bh * NB + kb) * 4 + f) * 64 + lane) * 8) = frag;
        }
    } else {
        // ---- block mask with early-exit ----
        const int b3 = bid - 4096;
        const int h  = b3 >> 6;
        const int br = b3 & 63;
        float bv = bias[h];
        unsigned char* outp = bm + ((size_t)h * NB + br) * NB;
        if (bv > 0.f) {
            if (t < NB) outp[t] = 1;
            return;
        }
        int bc0 = t >> 3;
        int bc1 = 32 + bc0;
        const int* base = mask + ((size_t)h * Sc + (size_t)br * 32) * (size_t)Sc;
        const int* p0 = base + 4 * t;
        const int* p1 = base + 1024 + 4 * t;
        bool d0 = (bc0 <= br), d1 = (bc1 <= br);
        int acc0 = 0, acc1 = 0;
        if (d0) {
#pragma unroll
            for (int r = 0; r < 4; r++) {
                i32x4 vv = *(const i32x4*)(p0 + (size_t)r * Sc);
                acc0 += vv[0] + vv[1] + vv[2] + vv[3];
            }
        }
        if (d1) {
#pragma unroll
            for (int r = 0; r < 4; r++) {
                i32x4 vv = *(const i32x4*)(p1 + (size_t)r * Sc);
                acc1 += vv[0] + vv[1] + vv[2] + vv[3];
            }
        }
        int g0 = acc0, g1 = acc1;
#pragma unroll
        for (int off = 1; off < 8; off <<= 1) {
            g0 += __shfl_xor(g0, off);
            g1 += __shfl_xor(g1, off);
        }
        bool act0 = (float)g0 + bv > 0.f;   // certified active (remaining rows >= 0)
        bool act1 = (float)g1 + bv > 0.f;
        if (d0 && !act0) {
            for (int r = 4; r < 32; r++) {
                i32x4 vv = *(const i32x4*)(p0 + (size_t)r * Sc);
                acc0 += vv[0] + vv[1] + vv[2] + vv[3];
            }
            int s = acc0;
#pragma unroll
            for (int off = 1; off < 8; off <<= 1) s += __shfl_xor(s, off);
            act0 = (float)s + bv > 0.f;
        }
        if (d1 && !act1) {
            for (int r = 4; r < 32; r++) {
                i32x4 vv = *(const i32x4*)(p1 + (size_t)r * Sc);
                acc1 += vv[0] + vv[1] + vv[2] + vv[3];
            }
            int s = acc1;
#pragma unroll
            for (int off = 1; off < 8; off <<= 1) s += __shfl_xor(s, off);
            act1 = (float)s + bv > 0.f;
        }
        if ((t & 7) == 0) {
            if (d0) outp[bc0] = act0 ? 1 : 0;
            if (d1) outp[bc1] = act1 ? 1 : 0;
        }
    }
}

// ---------- flash blocksparse causal attention: pairs + coalesced fragment loads -----
#if HAVE_PLSWAP
#define EXCHANGE_P(PB, B0, B1) do {                                            \
        i32x2 e0_ = plswap(PB[0], PB[2]);                                      \
        i32x2 e1_ = plswap(PB[1], PB[3]);                                      \
        i32x2 e2_ = plswap(PB[4], PB[6]);                                      \
        i32x2 e3_ = plswap(PB[5], PB[7]);                                      \
        B0.u[0] = (unsigned int)e0_[0]; B0.u[1] = (unsigned int)e1_[0];        \
        B0.u[2] = (unsigned int)e0_[1]; B0.u[3] = (unsigned int)e1_[1];        \
        B1.u[0] = (unsigned int)e2_[0]; B1.u[1] = (unsigned int)e3_[0];        \
        B1.u[2] = (unsigned int)e2_[1]; B1.u[3] = (unsigned int)e3_[1];        \
} while (0)
#else
#define EXCHANGE_P(PB, B0, B1) do {                                            \
        unsigned int qb_[8];                                                   \
        _Pragma("unroll")                                                      \
        for (int i_ = 0; i_ < 8; i_++)                                         \
            qb_[i_] = (unsigned int)__shfl_xor((int)PB[i_], 32);               \
        B0.u[0] = hi ? qb_[2] : PB[0]; B0.u[1] = hi ? qb_[3] : PB[1];          \
        B0.u[2] = hi ? PB[2] : qb_[0]; B0.u[3] = hi ? PB[3] : qb_[1];          \
        B1.u[0] = hi ? qb_[6] : PB[4]; B1.u[1] = hi ? qb_[7] : PB[5];          \
        B1.u[2] = hi ? PB[6] : qb_[4]; B1.u[3] = hi ? PB[7] : qb_[5];          \
} while (0)
#endif

// one tile-chain update; operands from coalesced fragment arrays (kbuf_/va_)
#define CORE(OT0, OT1, MR, LR, QH, BROW, kb_) do {                             \
        f32x16 st;                                                             \
        _Pragma("unroll")                                                      \
        for (int r_ = 0; r_ < 16; r_++) st[r_] = 0.f;                          \
        _Pragma("unroll")                                                      \
        for (int kc_ = 0; kc_ < 4; kc_++)                                      \
            st = mfma32(kbuf_[kc_], QH[kc_], st);                              \
        if ((kb_) == (BROW)) {                                                 \
            _Pragma("unroll")                                                  \
            for (int r_ = 0; r_ < 16; r_++) {                                  \
                int kvl_ = (r_ & 3) + 8 * (r_ >> 2) + 4 * hi;                  \
                if (kvl_ > l31) st[r_] = -1e30f;                               \
            }                                                                  \
        }                                                                      \
        float a0_ = fmaxf(fmaxf(st[0], st[1]), st[2]);                         \
        float a1_ = fmaxf(fmaxf(st[3], st[4]), st[5]);                         \
        float a2_ = fmaxf(fmaxf(st[6], st[7]), st[8]);                         \
        float a3_ = fmaxf(fmaxf(st[9], st[10]), st[11]);                       \
        float a4_ = fmaxf(fmaxf(st[12], st[13]), st[14]);                      \
        float b0m_ = fmaxf(fmaxf(a0_, a1_), a2_);                              \
        float b1m_ = fmaxf(fmaxf(a3_, a4_), st[15]);                           \
        float mx_ = xhalf_max(fmaxf(b0m_, b1m_));                              \
        if (__ballot(mx_ > MR + 11.0f)) {                                      \
            float mn_ = fmaxf(MR, mx_);                                        \
            float al_ = fexp2(MR - mn_);                                       \
            MR = mn_;                                                          \
            LR *= al_;                                                         \
            OT0 *= al_; OT1 *= al_;                                            \
        }                                                                      \
        _Pragma("unroll")                                                      \
        for (int r_ = 0; r_ < 16; r_++) st[r_] = fexp2(st[r_] - MR);           \
        {                                                                      \
            float s0 = (st[0] + st[1]) + (st[2] + st[3]);                      \
            float s1 = (st[4] + st[5]) + (st[6] + st[7]);                      \
            float s2 = (st[8] + st[9]) + (st[10] + st[11]);                    \
            float s3 = (st[12] + st[13]) + (st[14] + st[15]);                  \
            LR += ((s0 + s1) + (s2 + s3));                                     \
        }                                                                      \
        unsigned int pb_[8];                                                   \
        _Pragma("unroll")                                                      \
        for (int i_ = 0; i_ < 8; i_++) {                                       \
            PK pk_;                                                            \
            pk_.h = __builtin_amdgcn_cvt_pkrtz(st[2 * i_], st[2 * i_ + 1]);    \
            pb_[i_] = pk_.u;                                                   \
        }                                                                      \
        UB b0_, b1_;                                                           \
        EXCHANGE_P(pb_, b0_, b1_);                                             \
        OT0 = mfma32(va_[0][0], b0_.v, OT0);                                   \
        OT0 = mfma32(va_[0][1], b1_.v, OT0);                                   \
        OT1 = mfma32(va_[1][0], b0_.v, OT1);                                   \
        OT1 = mfma32(va_[1][1], b1_.v, OT1);                                   \
} while (0)

#define QLOAD(QH, q0_) do {                                                    \
        const float* qr_ = q_ptr + (size_t)((q0_) + l31) * Dc + hi * 8;        \
        _Pragma("unroll")                                                      \
        for (int kc_ = 0; kc_ < 4; kc_++) {                                    \
            f32x4 a_ = *(const f32x4*)(qr_ + kc_ * 16);                        \
            f32x4 b_ = *(const f32x4*)(qr_ + kc_ * 16 + 4);                    \
            float xs_[8] = {a_[0], a_[1], a_[2], a_[3], b_[0], b_[1], b_[2], b_[3]}; \
            _Pragma("unroll")                                                  \
            for (int j_ = 0; j_ < 8; j_++) QH[kc_][j_] = (f16_t)(xs_[j_] * LOG2E); \
        }                                                                      \
} while (0)

#define POST(OT0, OT1, MR, LS) do {                                            \
        _Pragma("unroll")                                                      \
        for (int r_ = 0; r_ < 16; r_++) {                                      \
            int d0_ = (r_ & 3) + 8 * (r_ >> 2) + 4 * hi;                       \
            lds_o[d0_ * 33 + l31]        = OT0[r_];                            \
            lds_o[(d0_ + 32) * 33 + l31] = OT1[r_];                            \
        }                                                                      \
        if (hi == 0) { lds_m[l31] = MR; lds_l[l31] = LS; }                     \
} while (0)

#define MERGE_WRITE(OT0, OT1, MR, LS, q0_) do {                                \
        float m1_ = lds_m[l31], l1_ = lds_l[l31];                              \
        float mm_ = fmaxf(MR, m1_);                                            \
        float c0_ = (MR  > -1e37f) ? fexp2(MR  - mm_) : 0.f;                   \
        float c1_ = (m1_ > -1e37f) ? fexp2(m1_ - mm_) : 0.f;                   \
        float lt_ = LS * c0_ + l1_ * c1_;                                      \
        float inv_ = (lt_ > 0.f) ? (1.f / lt_) : 0.f;                          \
        float* op_ = Out + bh_off + (size_t)((q0_) + l31) * Dc;                \
        _Pragma("unroll")                                                      \
        for (int g_ = 0; g_ < 4; g_++) {                                       \
            f32x4 w0_, w1_;                                                    \
            _Pragma("unroll")                                                  \
            for (int jj_ = 0; jj_ < 4; jj_++) {                                \
                int r_ = g_ * 4 + jj_;                                         \
                int d0_ = jj_ + 8 * g_ + 4 * hi;                               \
                w0_[jj_] = (OT0[r_] * c0_ + lds_o[d0_ * 33 + l31] * c1_) * inv_;        \
                w1_[jj_] = (OT1[r_] * c0_ + lds_o[(d0_ + 32) * 33 + l31] * c1_) * inv_; \
            }                                                                  \
            *(f32x4*)(op_ + g_ * 8 + hi * 4)      = w0_;                       \
            *(f32x4*)(op_ + 32 + g_ * 8 + hi * 4) = w1_;                       \
        }                                                                      \
} while (0)

__global__ __launch_bounds__(128, 2) void k_attn(const float* __restrict__ Q,
                                                 const f16_t* __restrict__ KHF,
                                                 const f16_t* __restrict__ VAF,
                                                 const unsigned char* __restrict__ BM,
                                                 float* __restrict__ Out) {
    __shared__ float lds_o[64 * 33];
    __shared__ float lds_m[32];
    __shared__ float lds_l[32];

    const int pair = blockIdx.x >> 5;              // 0..31
    const int bh   = blockIdx.x & 31;
    const int h    = bh & (Hc - 1);
    const int w    = threadIdx.x >> 6;
    const int lane = threadIdx.x & 63;
    const int l31  = lane & 31, hi = lane >> 5;

    const size_t bh_off = (size_t)bh * Sc * Dc;
    const float* q_ptr  = Q + bh_off;
    const f16_t* khfp   = KHF + (size_t)bh * FRAG_BH;
    const f16_t* vafp   = VAF + (size_t)bh * FRAG_BH;

    const int qiA = pair, qiB = 63 - pair;         // qiA <= 31 < qiB
    const unsigned char* bmA = BM + ((size_t)h * NB + qiA) * NB;
    const unsigned char* bmB = BM + ((size_t)h * NB + qiB) * NB;
    const unsigned long long amA = __ballot(bmA[lane] != 0);
    const unsigned long long amB = __ballot(bmB[lane] != 0);

    f16x8 qhA[4], qhB[4];
    QLOAD(qhA, qiA * 32);
    QLOAD(qhB, qiB * 32);

    f32x16 oA0, oA1, oB0, oB1;
#pragma unroll
    for (int r = 0; r < 16; r++) { oA0[r] = 0.f; oA1[r] = 0.f; oB0[r] = 0.f; oB1[r] = 0.f; }
    float mA = -INFINITY, lA = 0.f, mB = -INFINITY, lB = 0.f;

    // this wave handles kb == w (mod 2); all operand loads coalesced (base + lane*16B)
    for (int kb = w; kb <= qiB; kb += 2) {
        const bool aA = (kb <= qiA) && ((amA >> kb) & 1ull);
        const bool aB = (amB >> kb) & 1ull;
        if (!(aA || aB)) continue;
        f16x8 kbuf_[4];
#pragma unroll
        for (int kc = 0; kc < 4; kc++)
            kbuf_[kc] = *(const f16x8*)(khfp + (((size_t)kb * 4 + kc) * 64 + lane) * 8);
        f16x8 va_[2][2];
#pragma unroll
        for (int t = 0; t < 2; t++)
#pragma unroll
            for (int c = 0; c < 2; c++)
                va_[t][c] = *(const f16x8*)(vafp + (((size_t)kb * 4 + t * 2 + c) * 64 + lane) * 8);
        if (aA) CORE(oA0, oA1, mA, lA, qhA, qiA, kb);
        if (aB) CORE(oB0, oB1, mB, lB, qhB, qiB, kb);
    }

    const float lsA = xhalf_sum(lA);
    const float lsB = xhalf_sum(lB);

    // two-phase merge through one LDS buffer (epilogue only)
    if (w == 1) POST(oA0, oA1, mA, lsA);
    __syncthreads();
    if (w == 0) MERGE_WRITE(oA0, oA1, mA, lsA, qiA * 32);
    __syncthreads();
    if (w == 0) POST(oB0, oB1, mB, lsB);
    __syncthreads();
    if (w == 1) MERGE_WRITE(oB0, oB1, mB, lsB, qiB * 32);
}

extern "C" void kernel_launch(void* const* d_in, const int* in_sizes, int n_in,
                              void* d_out, int out_size, void* d_ws, size_t ws_size,
                              hipStream_t stream) {
    const float* Q    = (const float*)d_in[0];
    const float* K    = (const float*)d_in[1];
    const float* V    = (const float*)d_in[2];
    const float* bias = (const float*)d_in[3];
    const int*   mask = (const int*)d_in[4];
    float* out = (float*)d_out;

    char* ws = (char*)d_ws;
    f16_t* khf = (f16_t*)ws;                                    // 8 MiB
    f16_t* vaf = (f16_t*)(ws + (size_t)32 * FRAG_BH * 2);       // 8 MiB
    unsigned char* bm = (unsigned char*)(ws + (size_t)64 * FRAG_BH * 2);  // 64 KiB

    k_prep <<<5120, 256, 0, stream>>>(K, V, mask, bias, khf, vaf, bm);
    k_attn <<<Hc * Bc * (NB / 2), 128, 0, stream>>>(Q, khf, vaf, bm, out);
}